// Round 1
// baseline (352.970 us; speedup 1.0000x reference)
//
#include <hip/hip_runtime.h>
#include <math.h>

#define B_  8
#define R_  64
#define C_  256
#define NH_ 8
#define N_  4096
#define HD_ 32

// ---------------------------------------------------------------------------
// Kernel A: focused kernelization. One wave (64 lanes) per token; lane l owns
// channels 4l..4l+3. Full-C (256) norms via wave shuffle reduction.
// Writes qf/kf in (B*NH, N, HD) layout for the per-head kernels downstream.
// ---------------------------------------------------------------------------
__global__ __launch_bounds__(256) void kernelA(
        const float* __restrict__ qkv, const float* __restrict__ pos,
        const float* __restrict__ scale,
        float* __restrict__ qf, float* __restrict__ kf) {
    const int t    = threadIdx.x;
    const int wave = t >> 6, lane = t & 63;
    const int tok  = blockIdx.x * 4 + wave;
    const int b    = tok >> 12;          // tok / N_
    const int n    = tok & (N_ - 1);
    const int c0   = lane * 4;

    const size_t qidx = ((size_t)(b * N_ + n)) * C_ + c0;
    const float4 q4 = *(const float4*)(qkv + qidx);
    const float4 k4 = *(const float4*)(qkv + (size_t)B_ * N_ * C_ + qidx);
    const float4 p4 = *(const float4*)(pos + (size_t)n * C_ + c0);
    const float4 s4 = *(const float4*)(scale + c0);

    float qa[4] = {q4.x, q4.y, q4.z, q4.w};
    float kk[4] = {k4.x, k4.y, k4.z, k4.w};
    float pa[4] = {p4.x, p4.y, p4.z, p4.w};
    float sa[4] = {s4.x, s4.y, s4.z, s4.w};

    float q3[4], k3[4];
    float sq2 = 0.f, sq6 = 0.f, sk2 = 0.f, sk6 = 0.f;
    #pragma unroll
    for (int i = 0; i < 4; i++) {
        const float sc = log1pf(expf(sa[i]));          // softplus
        float qv = (fmaxf(qa[i], 0.f) + 1e-6f) / sc;
        float kv = (fmaxf(kk[i] + pa[i], 0.f) + 1e-6f) / sc;
        sq2 += qv * qv;  sk2 += kv * kv;
        const float q3v = qv * qv * qv;
        const float k3v = kv * kv * kv;
        q3[i] = q3v;  k3[i] = k3v;
        sq6 += q3v * q3v;  sk6 += k3v * k3v;
    }
    #pragma unroll
    for (int m = 1; m < 64; m <<= 1) {
        sq2 += __shfl_xor(sq2, m, 64);
        sq6 += __shfl_xor(sq6, m, 64);
        sk2 += __shfl_xor(sk2, m, 64);
        sk6 += __shfl_xor(sk6, m, 64);
    }
    const float qs = sqrtf(sq2) * rsqrtf(sq6);   // ||q|| / ||q^3||
    const float ks = sqrtf(sk2) * rsqrtf(sk6);

    const int h = c0 >> 5, d = c0 & 31;
    const size_t ob = (size_t)b * N_ * C_ + (size_t)h * N_ * HD_
                    + (size_t)n * HD_ + d;
    *(float4*)(qf + ob) = make_float4(q3[0]*qs, q3[1]*qs, q3[2]*qs, q3[3]*qs);
    *(float4*)(kf + ob) = make_float4(k3[0]*ks, k3[1]*ks, k3[2]*ks, k3[3]*ks);
}

// ---------------------------------------------------------------------------
// Kernel B: kv[c][d] = sum_n k[n][c] * v[n][d] and ksum[c] = sum_n k[n][c],
// per head-batch (64 of them). 8 n-chunks per head -> 512 blocks, atomicAdd
// into zero-initialized kv_ws/ksum_ws. LDS-tiled (128 tokens per tile).
// Thread t owns (c = t>>3, d = (t&7)*4 .. +3).
// ---------------------------------------------------------------------------
__global__ __launch_bounds__(256) void kernelB(
        const float* __restrict__ kf, const float* __restrict__ qkv,
        float* __restrict__ kv_ws, float* __restrict__ ksum_ws) {
    __shared__ float k_s[128 * HD_];
    __shared__ float v_s[128 * HD_];
    const int t     = threadIdx.x;
    const int bh    = blockIdx.x >> 3;
    const int chunk = blockIdx.x & 7;
    const int b     = bh >> 3, h = bh & 7;
    const int c     = t >> 3, p = t & 7, dbase = p * 4;

    float a0 = 0.f, a1 = 0.f, a2 = 0.f, a3 = 0.f, ksp = 0.f;
    const size_t vbase = (size_t)2 * B_ * N_ * C_ + (size_t)b * N_ * C_ + h * HD_;

    for (int tile = 0; tile < 4; tile++) {
        const int n0 = chunk * 512 + tile * 128;
        // k tile: flat contiguous 4096 floats
        const float4* ksrc = (const float4*)(kf + (size_t)bh * N_ * HD_ + (size_t)n0 * HD_);
        #pragma unroll
        for (int i = 0; i < 4; i++)
            ((float4*)k_s)[i * 256 + t] = ksrc[i * 256 + t];
        // v tile: rows of 32 floats strided by C_
        #pragma unroll
        for (int i = 0; i < 4; i++) {
            const int j  = (i * 256 + t) * 4;
            const int nl = j >> 5, d = j & 31;
            ((float4*)v_s)[i * 256 + t] =
                *(const float4*)(qkv + vbase + (size_t)(n0 + nl) * C_ + d);
        }
        __syncthreads();
        #pragma unroll 4
        for (int nl = 0; nl < 128; nl++) {
            const float  kc = k_s[nl * HD_ + c];
            const float4 vv = *(const float4*)&v_s[nl * HD_ + dbase];
            a0 = fmaf(kc, vv.x, a0);
            a1 = fmaf(kc, vv.y, a1);
            a2 = fmaf(kc, vv.z, a2);
            a3 = fmaf(kc, vv.w, a3);
        }
        #pragma unroll
        for (int i = 0; i < 16; i++)
            ksp += k_s[(p + i * 8) * HD_ + c];
        __syncthreads();
    }
    float* kvdst = kv_ws + (size_t)bh * 1024 + c * HD_ + dbase;
    atomicAdd(kvdst + 0, a0);
    atomicAdd(kvdst + 1, a1);
    atomicAdd(kvdst + 2, a2);
    atomicAdd(kvdst + 3, a3);
    // ksum: reduce 8 partials per c through LDS (reuse k_s)
    k_s[c * 8 + p] = ksp;
    __syncthreads();
    if (t < 32) {
        float s = 0.f;
        #pragma unroll
        for (int i = 0; i < 8; i++) s += k_s[t * 8 + i];
        atomicAdd(&ksum_ws[bh * HD_ + t], s);
    }
}

// ---------------------------------------------------------------------------
// Kernel C: x[n][d] = z * sum_c q[n][c] * kv[c][d];  z = 1/(q·ksum + 1e-6).
// One thread per token; kv (4 KB) + ksum in LDS (broadcast reads).
// Writes x directly into d_out in (B,N,C) layout.
// ---------------------------------------------------------------------------
__global__ __launch_bounds__(256) void kernelC(
        const float* __restrict__ qf, const float* __restrict__ kv_ws,
        const float* __restrict__ ksum_ws, float* __restrict__ out) {
    __shared__ float kv_s[1024];
    __shared__ float ks_s[32];
    const int t  = threadIdx.x;
    const int bh = blockIdx.y;
    const int n  = blockIdx.x * 256 + t;
    const int b  = bh >> 3, h = bh & 7;

    ((float4*)kv_s)[t] = ((const float4*)(kv_ws + (size_t)bh * 1024))[t];
    if (t < 32) ks_s[t] = ksum_ws[bh * HD_ + t];
    __syncthreads();

    float q[32];
    const float4* qsrc = (const float4*)(qf + (size_t)bh * N_ * HD_ + (size_t)n * HD_);
    #pragma unroll
    for (int i = 0; i < 8; i++) ((float4*)q)[i] = qsrc[i];

    float denom = 1e-6f;
    #pragma unroll
    for (int cc = 0; cc < 32; cc++) denom = fmaf(q[cc], ks_s[cc], denom);
    const float z = 1.f / denom;

    float o[32];
    #pragma unroll
    for (int i = 0; i < 32; i++) o[i] = 0.f;
    #pragma unroll
    for (int cc = 0; cc < 32; cc++) {
        const float qc = q[cc];
        #pragma unroll
        for (int d = 0; d < 32; d++)
            o[d] = fmaf(qc, kv_s[cc * 32 + d], o[d]);
    }
    float* dst = out + ((size_t)(b * N_ + n)) * C_ + h * HD_;
    #pragma unroll
    for (int i = 0; i < 8; i++) {
        float4 v;
        v.x = o[i*4+0] * z;  v.y = o[i*4+1] * z;
        v.z = o[i*4+2] * z;  v.w = o[i*4+3] * z;
        ((float4*)dst)[i] = v;
    }
}

// ---------------------------------------------------------------------------
// Kernel D: depthwise convs epilogue. Both lepe (3x3, weight per channel c)
// and fm (5x5, weight per c&31) convolve the SAME v image (B, C, 64, 64);
// fuse into one 5x5 window walk. Block = one (b, y, x); thread = channel.
// RMW d_out (+= conv terms + biases).
// ---------------------------------------------------------------------------
__global__ __launch_bounds__(256) void kernelD(
        const float* __restrict__ qkv,
        const float* __restrict__ w_v,  const float* __restrict__ b_v,
        const float* __restrict__ w_dwc, const float* __restrict__ b_dwc,
        float* __restrict__ out) {
    const int c = threadIdx.x;
    const int n = blockIdx.x;
    const int b = blockIdx.y;
    const int y = n >> 6, x = n & 63;

    float wv[9], wd[25];
    #pragma unroll
    for (int i = 0; i < 9; i++)  wv[i] = w_v[c * 9 + i];
    #pragma unroll
    for (int i = 0; i < 25; i++) wd[i] = w_dwc[(c & 31) * 25 + i];

    const float* vb = qkv + (size_t)2 * B_ * N_ * C_ + (size_t)b * N_ * C_;
    float acc = b_v[c] + b_dwc[c & 31];
    #pragma unroll
    for (int di = -2; di <= 2; di++) {
        const int yy = y + di;
        if (yy < 0 || yy >= R_) continue;
        #pragma unroll
        for (int dj = -2; dj <= 2; dj++) {
            const int xx = x + dj;
            if (xx < 0 || xx >= R_) continue;
            const float v = vb[(size_t)(yy * R_ + xx) * C_ + c];
            acc = fmaf(wd[(di + 2) * 5 + (dj + 2)], v, acc);
            if (di >= -1 && di <= 1 && dj >= -1 && dj <= 1)
                acc = fmaf(wv[(di + 1) * 3 + (dj + 1)], v, acc);
        }
    }
    const size_t oi = ((size_t)(b * N_ + n)) * C_ + c;
    out[oi] += acc;
}

// ---------------------------------------------------------------------------
extern "C" void kernel_launch(void* const* d_in, const int* in_sizes, int n_in,
                              void* d_out, int out_size, void* d_ws, size_t ws_size,
                              hipStream_t stream) {
    const float* qkv   = (const float*)d_in[0];
    const float* pos   = (const float*)d_in[1];
    const float* scale = (const float*)d_in[2];
    const float* w_v   = (const float*)d_in[3];
    const float* b_v   = (const float*)d_in[4];
    const float* w_dwc = (const float*)d_in[5];
    const float* b_dwc = (const float*)d_in[6];
    float* out = (float*)d_out;

    float* qf      = (float*)d_ws;                       // B*N*C floats
    float* kf      = qf + (size_t)B_ * N_ * C_;          // B*N*C floats
    float* kv_ws   = kf + (size_t)B_ * N_ * C_;          // 64*1024 floats
    float* ksum_ws = kv_ws + 64 * 1024;                  // 64*32 floats

    hipMemsetAsync(kv_ws, 0, (64 * 1024 + 64 * 32) * sizeof(float), stream);
    kernelA<<<dim3(B_ * N_ / 4), 256, 0, stream>>>(qkv, pos, scale, qf, kf);
    kernelB<<<dim3(512), 256, 0, stream>>>(kf, qkv, kv_ws, ksum_ws);
    kernelC<<<dim3(16, 64), 256, 0, stream>>>(qf, kv_ws, ksum_ws, out);
    kernelD<<<dim3(N_, B_), 256, 0, stream>>>(qkv, w_v, b_v, w_dwc, b_dwc, out);
}

// Round 2
// 234.932 us; speedup vs baseline: 1.5024x; 1.5024x over previous
//
#include <hip/hip_runtime.h>
#include <math.h>

#define B_  8
#define R_  64
#define C_  256
#define NH_ 8
#define N_  4096
#define HD_ 32

// ---------------------------------------------------------------------------
// Kernel A: focused kernelization. One wave (64 lanes) per token; lane l owns
// channels 4l..4l+3. Full-C (256) norms via wave shuffle reduction.
// Writes qf/kf in (B*NH, N, HD) layout for the per-head kernels downstream.
// ---------------------------------------------------------------------------
__global__ __launch_bounds__(256) void kernelA(
        const float* __restrict__ qkv, const float* __restrict__ pos,
        const float* __restrict__ scale,
        float* __restrict__ qf, float* __restrict__ kf) {
    const int t    = threadIdx.x;
    const int wave = t >> 6, lane = t & 63;
    const int tok  = blockIdx.x * 4 + wave;
    const int b    = tok >> 12;          // tok / N_
    const int n    = tok & (N_ - 1);
    const int c0   = lane * 4;

    const size_t qidx = ((size_t)(b * N_ + n)) * C_ + c0;
    const float4 q4 = *(const float4*)(qkv + qidx);
    const float4 k4 = *(const float4*)(qkv + (size_t)B_ * N_ * C_ + qidx);
    const float4 p4 = *(const float4*)(pos + (size_t)n * C_ + c0);
    const float4 s4 = *(const float4*)(scale + c0);

    float qa[4] = {q4.x, q4.y, q4.z, q4.w};
    float kk[4] = {k4.x, k4.y, k4.z, k4.w};
    float pa[4] = {p4.x, p4.y, p4.z, p4.w};
    float sa[4] = {s4.x, s4.y, s4.z, s4.w};

    float q3[4], k3[4];
    float sq2 = 0.f, sq6 = 0.f, sk2 = 0.f, sk6 = 0.f;
    #pragma unroll
    for (int i = 0; i < 4; i++) {
        const float sc = log1pf(expf(sa[i]));          // softplus
        float qv = (fmaxf(qa[i], 0.f) + 1e-6f) / sc;
        float kv = (fmaxf(kk[i] + pa[i], 0.f) + 1e-6f) / sc;
        sq2 += qv * qv;  sk2 += kv * kv;
        const float q3v = qv * qv * qv;
        const float k3v = kv * kv * kv;
        q3[i] = q3v;  k3[i] = k3v;
        sq6 += q3v * q3v;  sk6 += k3v * k3v;
    }
    #pragma unroll
    for (int m = 1; m < 64; m <<= 1) {
        sq2 += __shfl_xor(sq2, m, 64);
        sq6 += __shfl_xor(sq6, m, 64);
        sk2 += __shfl_xor(sk2, m, 64);
        sk6 += __shfl_xor(sk6, m, 64);
    }
    const float qs = sqrtf(sq2) * rsqrtf(sq6);   // ||q|| / ||q^3||
    const float ks = sqrtf(sk2) * rsqrtf(sk6);

    const int h = c0 >> 5, d = c0 & 31;
    const size_t ob = (size_t)b * N_ * C_ + (size_t)h * N_ * HD_
                    + (size_t)n * HD_ + d;
    *(float4*)(qf + ob) = make_float4(q3[0]*qs, q3[1]*qs, q3[2]*qs, q3[3]*qs);
    *(float4*)(kf + ob) = make_float4(k3[0]*ks, k3[1]*ks, k3[2]*ks, k3[3]*ks);
}

// ---------------------------------------------------------------------------
// Kernel B: kv[c][d] = sum_n k[n][c] * v[n][d] and ksum[c] = sum_n k[n][c],
// per head-batch (64). 8 n-chunks per head -> 512 blocks, atomicAdd into
// zero-initialized kv_ws/ksum_ws. LDS-tiled (128 tokens per tile).
// ---------------------------------------------------------------------------
__global__ __launch_bounds__(256) void kernelB(
        const float* __restrict__ kf, const float* __restrict__ qkv,
        float* __restrict__ kv_ws, float* __restrict__ ksum_ws) {
    __shared__ float k_s[128 * HD_];
    __shared__ float v_s[128 * HD_];
    const int t     = threadIdx.x;
    const int bh    = blockIdx.x >> 3;
    const int chunk = blockIdx.x & 7;
    const int b     = bh >> 3, h = bh & 7;
    const int c     = t >> 3, p = t & 7, dbase = p * 4;

    float a0 = 0.f, a1 = 0.f, a2 = 0.f, a3 = 0.f, ksp = 0.f;
    const size_t vbase = (size_t)2 * B_ * N_ * C_ + (size_t)b * N_ * C_ + h * HD_;

    for (int tile = 0; tile < 4; tile++) {
        const int n0 = chunk * 512 + tile * 128;
        const float4* ksrc = (const float4*)(kf + (size_t)bh * N_ * HD_ + (size_t)n0 * HD_);
        #pragma unroll
        for (int i = 0; i < 4; i++)
            ((float4*)k_s)[i * 256 + t] = ksrc[i * 256 + t];
        #pragma unroll
        for (int i = 0; i < 4; i++) {
            const int j  = (i * 256 + t) * 4;
            const int nl = j >> 5, d = j & 31;
            ((float4*)v_s)[i * 256 + t] =
                *(const float4*)(qkv + vbase + (size_t)(n0 + nl) * C_ + d);
        }
        __syncthreads();
        #pragma unroll 4
        for (int nl = 0; nl < 128; nl++) {
            const float  kc = k_s[nl * HD_ + c];
            const float4 vv = *(const float4*)&v_s[nl * HD_ + dbase];
            a0 = fmaf(kc, vv.x, a0);
            a1 = fmaf(kc, vv.y, a1);
            a2 = fmaf(kc, vv.z, a2);
            a3 = fmaf(kc, vv.w, a3);
        }
        #pragma unroll
        for (int i = 0; i < 16; i++)
            ksp += k_s[(p + i * 8) * HD_ + c];
        __syncthreads();
    }
    float* kvdst = kv_ws + (size_t)bh * 1024 + c * HD_ + dbase;
    atomicAdd(kvdst + 0, a0);
    atomicAdd(kvdst + 1, a1);
    atomicAdd(kvdst + 2, a2);
    atomicAdd(kvdst + 3, a3);
    k_s[c * 8 + p] = ksp;
    __syncthreads();
    if (t < 32) {
        float s = 0.f;
        #pragma unroll
        for (int i = 0; i < 8; i++) s += k_s[t * 8 + i];
        atomicAdd(&ksum_ws[bh * HD_ + t], s);
    }
}

// ---------------------------------------------------------------------------
// Kernel CD: fused attention epilogue + both depthwise convs; out written ONCE.
// Block = 16x16 pixel tile x 1 head (32 ch). LDS: 20x20 halo'd v tile.
// Phase 1 (c-major threads): 5x5+3x3 conv via register ring window
//   (~5.6 LDS reads/px); results exchanged through LDS in pad-33 layout.
// Phase 2 (pixel-major threads): x = z * q . kv (kv/ksum broadcast from LDS)
//   + conv term; single float4 store stream to out.
// ---------------------------------------------------------------------------
__global__ __launch_bounds__(256) void kernelCD(
        const float* __restrict__ qkv, const float* __restrict__ qf,
        const float* __restrict__ kv_ws, const float* __restrict__ ksum_ws,
        const float* __restrict__ w_v,  const float* __restrict__ b_v,
        const float* __restrict__ w_dwc, const float* __restrict__ b_dwc,
        float* __restrict__ out) {
    __shared__ float v_s[20 * 20 * 32];   // 51.2 KB; reused as conv_s (256*33)
    __shared__ float kv_s[1024];
    __shared__ float ks_s[32];
    const int t    = threadIdx.x;
    const int tile = blockIdx.x;           // 0..15
    const int h    = blockIdx.y;
    const int b    = blockIdx.z;
    const int ty0  = (tile >> 2) * 16, tx0 = (tile & 3) * 16;
    const int bh   = b * NH_ + h;

    // stage kv + ksum
    ((float4*)kv_s)[t] = ((const float4*)(kv_ws + (size_t)bh * 1024))[t];
    if (t < 32) ks_s[t] = ksum_ws[bh * HD_ + t];

    // stage v tile (20x20 px x 32 ch = 3200 float4), zero-fill halo OOB
    const float* vb = qkv + (size_t)2 * B_ * N_ * C_ + (size_t)b * N_ * C_ + h * HD_;
    #pragma unroll
    for (int i = 0; i < 13; i++) {
        const int idx = i * 256 + t;
        if (idx < 3200) {
            const int pix = idx >> 3, d4 = (idx & 7) * 4;
            const int yy = pix / 20, xx = pix - yy * 20;
            const int gy = ty0 + yy - 2, gx = tx0 + xx - 2;
            float4 val = make_float4(0.f, 0.f, 0.f, 0.f);
            if (gy >= 0 && gy < R_ && gx >= 0 && gx < R_)
                val = *(const float4*)(vb + (size_t)(gy * R_ + gx) * C_ + d4);
            *(float4*)&v_s[pix * 32 + d4] = val;
        }
    }

    // conv weights (load before barrier to overlap latency)
    const int c  = t & 31, pg = t >> 5;
    float wv[9], wd[25];
    {
        const float* wvp = w_v + (size_t)(h * HD_ + c) * 9;
        const float* wdp = w_dwc + (size_t)c * 25;
        #pragma unroll
        for (int i = 0; i < 9; i++)  wv[i] = wvp[i];
        #pragma unroll
        for (int i = 0; i < 25; i++) wd[i] = wdp[i];
    }
    const float bias = b_v[h * HD_ + c] + b_dwc[c];
    __syncthreads();

    // ---- conv phase: thread = (channel c, 2 tile rows) ----
    float res[32];
    #pragma unroll
    for (int r2 = 0; r2 < 2; r2++) {
        const int ty = pg * 2 + r2;
        float win[5][5];                      // [col slot][row]
        #pragma unroll
        for (int j = 0; j < 5; j++)
            #pragma unroll
            for (int i = 0; i < 5; i++)
                win[j][i] = v_s[((ty + i) * 20 + j) * 32 + c];
        #pragma unroll
        for (int tx = 0; tx < 16; tx++) {
            float a = bias;
            #pragma unroll
            for (int j = 0; j < 5; j++) {     // j = dj+2 (window col)
                const int slot = (tx + j) % 5;
                #pragma unroll
                for (int i = 0; i < 5; i++)   // i = di+2 (window row)
                    a = fmaf(wd[i * 5 + j], win[slot][i], a);
            }
            #pragma unroll
            for (int j = 1; j < 4; j++) {
                const int slot = (tx + j) % 5;
                #pragma unroll
                for (int i = 1; i < 4; i++)
                    a = fmaf(wv[(i - 1) * 3 + (j - 1)], win[slot][i], a);
            }
            res[r2 * 16 + tx] = a;
            if (tx < 15) {                    // slide: replace oldest column
                const int slot = tx % 5;
                #pragma unroll
                for (int i = 0; i < 5; i++)
                    win[slot][i] = v_s[((ty + i) * 20 + (tx + 5)) * 32 + c];
            }
        }
    }
    __syncthreads();                          // all v_s reads complete
    #pragma unroll
    for (int r2 = 0; r2 < 2; r2++)
        #pragma unroll
        for (int tx = 0; tx < 16; tx++)
            v_s[((pg * 2 + r2) * 16 + tx) * 33 + c] = res[r2 * 16 + tx];
    __syncthreads();

    // ---- attention phase: thread = pixel ----
    {
        const int tyy = t >> 4, txx = t & 15;
        const int n   = (ty0 + tyy) * R_ + (tx0 + txx);
        float q[32];
        const float4* qsrc = (const float4*)(qf + (size_t)bh * N_ * HD_ + (size_t)n * HD_);
        #pragma unroll
        for (int i = 0; i < 8; i++) ((float4*)q)[i] = qsrc[i];

        float denom = 1e-6f;
        #pragma unroll
        for (int cc = 0; cc < 32; cc++) denom = fmaf(q[cc], ks_s[cc], denom);
        const float z = 1.f / denom;

        float o[32];
        #pragma unroll
        for (int i = 0; i < 32; i++) o[i] = 0.f;
        #pragma unroll
        for (int cc = 0; cc < 32; cc++) {
            const float qc = q[cc];
            #pragma unroll
            for (int d = 0; d < 32; d++)
                o[d] = fmaf(qc, kv_s[cc * 32 + d], o[d]);
        }
        float* dst = out + ((size_t)(b * N_ + n)) * C_ + h * HD_;
        #pragma unroll
        for (int i = 0; i < 8; i++) {
            float4 v4;
            v4.x = fmaf(o[i*4+0], z, v_s[t * 33 + i*4+0]);
            v4.y = fmaf(o[i*4+1], z, v_s[t * 33 + i*4+1]);
            v4.z = fmaf(o[i*4+2], z, v_s[t * 33 + i*4+2]);
            v4.w = fmaf(o[i*4+3], z, v_s[t * 33 + i*4+3]);
            ((float4*)dst)[i] = v4;
        }
    }
}

// ---------------------------------------------------------------------------
extern "C" void kernel_launch(void* const* d_in, const int* in_sizes, int n_in,
                              void* d_out, int out_size, void* d_ws, size_t ws_size,
                              hipStream_t stream) {
    const float* qkv   = (const float*)d_in[0];
    const float* pos   = (const float*)d_in[1];
    const float* scale = (const float*)d_in[2];
    const float* w_v   = (const float*)d_in[3];
    const float* b_v   = (const float*)d_in[4];
    const float* w_dwc = (const float*)d_in[5];
    const float* b_dwc = (const float*)d_in[6];
    float* out = (float*)d_out;

    float* qf      = (float*)d_ws;                       // B*N*C floats
    float* kf      = qf + (size_t)B_ * N_ * C_;          // B*N*C floats
    float* kv_ws   = kf + (size_t)B_ * N_ * C_;          // 64*1024 floats
    float* ksum_ws = kv_ws + 64 * 1024;                  // 64*32 floats

    hipMemsetAsync(kv_ws, 0, (64 * 1024 + 64 * 32) * sizeof(float), stream);
    kernelA<<<dim3(B_ * N_ / 4), 256, 0, stream>>>(qkv, pos, scale, qf, kf);
    kernelB<<<dim3(512), 256, 0, stream>>>(kf, qkv, kv_ws, ksum_ws);
    kernelCD<<<dim3(16, NH_, B_), 256, 0, stream>>>(qkv, qf, kv_ws, ksum_ws,
                                                    w_v, b_v, w_dwc, b_dwc, out);
}